// Round 2
// baseline (218.207 us; speedup 1.0000x reference)
//
#include <hip/hip_runtime.h>

typedef __attribute__((ext_vector_type(8))) short short8;
typedef __attribute__((ext_vector_type(4))) float floatx4;
// align(4) vector views for gathers from row-strided fp32 arrays.
// NOTE: no vec3 type here — clang ext_vector_type(3) is 16B storage, and a
// 16B load at fc+3*(N-1) reads past the buffer end (r6 container crash).
typedef __attribute__((ext_vector_type(2), aligned(4))) float f2a;
typedef __attribute__((ext_vector_type(4), aligned(4))) float f4a;

static constexpr float EPS = 1e-3f;

#define CAP 96      // max points/pillar; Binomial(1e6,1/3e4) P(>=97)~1e-18
#define CSTRIDE 32  // 1 counter per 128B line (atomic serialization fix, r4)

// ws layout (float offsets):
//   [0, NPIL*CSTRIDE)              cnt (ints)
//   prep = cnt_end (256-aligned):  w1f[224] | b1f[32] | w2l[1024] | b2f[32]
//                                  | w2uT (1024 ushorts = 512 floats) | pad
//   idx  = prep + 2048:            NPIL*CAP ints (point-index lists)
#define P_W1F  0
#define P_B1F  224
#define P_W2L  256
#define P_B2F  1280
#define P_W2UT 1312
#define PREP_F 2048

__device__ __forceinline__ unsigned short f2bf(float x) {
  unsigned u = __float_as_uint(x);
  u += 0x7FFFu + ((u >> 16) & 1u);          // RNE
  return (unsigned short)(u >> 16);
}

// ---- fold BN into weights once; emit bf16-transposed W2-upper ----
__global__ __launch_bounds__(256)
void k_prep(const float* __restrict__ W1, const float* __restrict__ g1,
            const float* __restrict__ b1, const float* __restrict__ m1,
            const float* __restrict__ v1,
            const float* __restrict__ W2, const float* __restrict__ g2,
            const float* __restrict__ b2, const float* __restrict__ m2,
            const float* __restrict__ v2, float* __restrict__ prep) {
  int t = threadIdx.x;
  for (int i = t; i < 224; i += 256) {
    int c = i & 31;
    prep[P_W1F + i] = W1[i] * (g1[c] * rsqrtf(v1[c] + EPS));
  }
  if (t < 32) {
    float s1 = g1[t] * rsqrtf(v1[t] + EPS);
    float s2 = g2[t] * rsqrtf(v2[t] + EPS);
    prep[P_B1F + t] = b1[t] - m1[t] * s1;
    prep[P_B2F + t] = b2[t] - m2[t] * s2;
  }
  unsigned short* wt = (unsigned short*)(prep + P_W2UT);
  for (int i = t; i < 1024; i += 256) {
    int k = i >> 5, c = i & 31;
    float s2 = g2[c] * rsqrtf(v2[c] + EPS);
    prep[P_W2L + i] = W2[(32 + k) * 32 + c] * s2;   // lower half, fp32
    wt[c * 32 + k] = f2bf(W2[k * 32 + c] * s2);     // upper half, bf16, [c][k]
  }
}

// ---- slot via padded int atomic; scatter ONLY the 4B point index ----
// (r5: was scattering 32B feature rows -> 64MB sector-amplified writebacks,
//  1.3 TB/s effective. Index scatter is ~10x less write traffic; the data
//  movement moves to k_pillar gathers served by L3: points+fc = 32MB < 256MB.)
__global__ __launch_bounds__(256)
void k_build_idx(const int* __restrict__ unq, int* __restrict__ cnt,
                 int* __restrict__ idx, int N) {
  int i = blockIdx.x * 256 + threadIdx.x;
  if (i >= N) return;
  int p = unq[i];
  int slot = atomicAdd(&cnt[p * CSTRIDE], 1);
  if (slot < CAP) idx[p * CAP + slot] = i;
}

// ---- one wave per pillar; MFMA for the 32x32 second linear ----
__global__ __launch_bounds__(256)
void k_pillar(const float* __restrict__ prep, const int* __restrict__ cnt,
              const int* __restrict__ idx, const float* __restrict__ points,
              const float* __restrict__ fc, float* __restrict__ out,
              int npil) {
  __shared__ __align__(16) float fbuf[4][CAP * 8];            // 12 KB
  __shared__ __align__(16) unsigned short hbuf[4][CAP * 32];  // 24 KB
  __shared__ __align__(16) unsigned short w2t[1024];          // 2 KB (block)
  __shared__ float sumb[4][32];

  const int t = threadIdx.x, w = t >> 6, lane = t & 63;

  // stage W2-upper^T (bf16) once per block
  ((uint2*)w2t)[t] = ((const uint2*)(prep + P_W2UT))[t];
  __syncthreads();   // only block-level barrier

  const int p = blockIdx.x * 4 + w;
  if (p >= npil) return;
  int n = cnt[p * CSTRIDE];
  n = n < CAP ? n : CAP;

  const int c = lane & 31, half = lane >> 5;

  // phase 0: gather this pillar's point rows via the index list.
  // idx reads are lane-coalesced; fc/points reads are random but L3-resident.
  // fc: 8B + 4B loads (in-bounds: last byte read = fc[3N-1]);
  // points: 16B load at row+1 (in-bounds: last byte read = points[5N-1]).
  const int* idxp = idx + (size_t)p * CAP;
  for (int q = lane; q < n; q += 64) {
    int i = idxp[q];
    f2a c2 = *(const f2a*)(fc + 3 * (size_t)i);
    float cz = fc[3 * (size_t)i + 2];
    f4a p4 = *(const f4a*)(points + 5 * (size_t)i + 1);
    floatx4 A, B;
    A.x = c2.x; A.y = c2.y; A.z = cz;  A.w = p4.x;
    B.x = p4.y; B.y = p4.z; B.z = p4.w; B.w = 0.f;
    floatx4* d4 = (floatx4*)(fbuf[w] + q * 8);
    d4[0] = A;
    d4[1] = B;
  }
  __builtin_amdgcn_wave_barrier();

  // folded weights (L1-hot across pillars)
  float w1c[7];
#pragma unroll
  for (int r = 0; r < 7; ++r) w1c[r] = prep[P_W1F + r * 32 + c];
  const float b1c = prep[P_B1F + c];
  const float b2c = prep[P_B2F + c];

  // phase 1: h = relu(f . w1f + b1f); fp32 partial sums; bf16 rows to LDS
  float ps = 0.f;
  for (int j = half; j < n; j += 2) {
    const float* f = fbuf[w] + j * 8;
    floatx4 fa = *(const floatx4*)f, fb = *(const floatx4*)(f + 4);
    float d = fa.x * w1c[0];
    d = fmaf(fa.y, w1c[1], d);
    d = fmaf(fa.z, w1c[2], d);
    d = fmaf(fa.w, w1c[3], d);
    d = fmaf(fb.x, w1c[4], d);
    d = fmaf(fb.y, w1c[5], d);
    d = fmaf(fb.z, w1c[6], d);
    float h = fmaxf(d + b1c, 0.f);
    ps += h;
    hbuf[w][j * 32 + c] = f2bf(h);
  }
  ps += __shfl_xor(ps, 32);          // cross-half channel sum
  if (half == 0) sumb[w][c] = ps;
  __builtin_amdgcn_wave_barrier();

  // phase 2: pc[c] = b2f + (sum_k sumh[k]*w2l[k][c]) / n   (same-wave LDS RAW)
  float acc = 0.f;
  const floatx4* sb4 = (const floatx4*)sumb[w];
#pragma unroll
  for (int kq = 0; kq < 8; ++kq) {
    floatx4 sv = sb4[kq];
    acc = fmaf(sv.x, prep[P_W2L + (kq * 4 + 0) * 32 + c], acc);
    acc = fmaf(sv.y, prep[P_W2L + (kq * 4 + 1) * 32 + c], acc);
    acc = fmaf(sv.z, prep[P_W2L + (kq * 4 + 2) * 32 + c], acc);
    acc = fmaf(sv.w, prep[P_W2L + (kq * 4 + 3) * 32 + c], acc);
  }
  const float inv_n = (n > 0) ? 1.f / (float)n : 1.f;
  const float pc = fmaf(inv_n, acc, b2c);

  // phase 3: Q = H(bf16) @ W2u via MFMA; masked max over rows
  const int m16 = lane & 15, q4 = lane >> 4;
  short8 bf0 = *(const short8*)(w2t + m16 * 32 + q4 * 8);
  short8 bf1 = *(const short8*)(w2t + (m16 + 16) * 32 + q4 * 8);
  float m0 = -INFINITY, m1 = -INFINITY;
  const int ntiles = (n + 15) >> 4;
  for (int rt = 0; rt < ntiles; ++rt) {
    short8 af = *(const short8*)(hbuf[w] + (rt * 16 + m16) * 32 + q4 * 8);
    floatx4 z = {0.f, 0.f, 0.f, 0.f};
    floatx4 a0 = __builtin_amdgcn_mfma_f32_16x16x32_bf16(af, bf0, z, 0, 0, 0);
    floatx4 a1 = __builtin_amdgcn_mfma_f32_16x16x32_bf16(af, bf1, z, 0, 0, 0);
    const int rowb = rt * 16 + q4 * 4;
#pragma unroll
    for (int r = 0; r < 4; ++r) {
      if (rowb + r < n) {          // mask tail-tile garbage rows
        m0 = fmaxf(m0, a0[r]);
        m1 = fmaxf(m1, a1[r]);
      }
    }
  }
  // reduce over the 4 row-groups (lanes differing in bits 4,5)
  m0 = fmaxf(m0, __shfl_xor(m0, 16));
  m0 = fmaxf(m0, __shfl_xor(m0, 32));
  m1 = fmaxf(m1, __shfl_xor(m1, 16));
  m1 = fmaxf(m1, __shfl_xor(m1, 32));

  if (lane < 32) {
    float q = (lane & 16) ? m1 : m0;     // cc = lane for lanes 0..31
    out[p * 32 + lane] = fmaxf(q + pc, 0.f);  // relu(max+pc): s2>0 monotone
  }
}

extern "C" void kernel_launch(void* const* d_in, const int* in_sizes, int n_in,
                              void* d_out, int out_size, void* d_ws, size_t ws_size,
                              hipStream_t stream) {
  const float* points = (const float*)d_in[0];
  const float* fc     = (const float*)d_in[1];
  const int*   unq    = (const int*)d_in[2];
  const float* W1 = (const float*)d_in[3];
  const float* g1 = (const float*)d_in[4];
  const float* b1 = (const float*)d_in[5];
  const float* m1 = (const float*)d_in[6];
  const float* v1 = (const float*)d_in[7];
  const float* W2 = (const float*)d_in[8];
  const float* g2 = (const float*)d_in[9];
  const float* b2 = (const float*)d_in[10];
  const float* m2 = (const float*)d_in[11];
  const float* v2 = (const float*)d_in[12];

  const int N    = in_sizes[0] / 5;  // 1,000,000
  const int NPIL = out_size / 32;    // 30,000

  float* ws = (float*)d_ws;
  int* cnt = (int*)ws;
  const size_t cnt_f  = ((size_t)NPIL * CSTRIDE + 255) & ~(size_t)255;
  float* prep = ws + cnt_f;
  int* idx = (int*)(prep + PREP_F);

  hipMemsetAsync(cnt, 0, (size_t)NPIL * CSTRIDE * sizeof(int), stream);

  k_prep<<<1, 256, 0, stream>>>(W1, g1, b1, m1, v1, W2, g2, b2, m2, v2, prep);

  const int nb = (N + 255) / 256;
  k_build_idx<<<nb, 256, 0, stream>>>(unq, cnt, idx, N);

  const int nbp = (NPIL + 3) / 4;
  k_pillar<<<nbp, 256, 0, stream>>>(prep, cnt, idx, points, fc, (float*)d_out, NPIL);
}

// Round 3
// 191.660 us; speedup vs baseline: 1.1385x; 1.1385x over previous
//
#include <hip/hip_runtime.h>

typedef __attribute__((ext_vector_type(8))) short short8;
typedef __attribute__((ext_vector_type(4))) float floatx4;

static constexpr float EPS = 1e-3f;

#define CAP 96      // max points/pillar; Binomial(1e6,1/3e4) P(>=97)~1e-18
#define CSTRIDE 32  // 1 counter per 128B line (atomic serialization fix, r4)
#define NGROUPS 256 // partition groups: grid = NGROUPS*8 blocks, b&7 = partition

// ws layout (float offsets):
//   [0, NPIL*CSTRIDE)              cnt (ints)
//   prep = cnt_end (256-aligned):  w1f[224] | b1f[32] | w2l[1024] | b2f[32]
//                                  | w2uT (1024 ushorts = 512 floats) | pad
//   idx  = prep + 2048:            NPIL*CAP ints (point-index lists)
//   row8 = idx + NPIL*CAP (256-al):N*8 floats, input-ordered compact rows
#define P_W1F  0
#define P_B1F  224
#define P_W2L  256
#define P_B2F  1280
#define P_W2UT 1312
#define PREP_F 2048

__device__ __forceinline__ unsigned short f2bf(float x) {
  unsigned u = __float_as_uint(x);
  u += 0x7FFFu + ((u >> 16) & 1u);          // RNE
  return (unsigned short)(u >> 16);
}

// ---- fold BN into weights once; emit bf16-transposed W2-upper ----
__global__ __launch_bounds__(256)
void k_prep(const float* __restrict__ W1, const float* __restrict__ g1,
            const float* __restrict__ b1, const float* __restrict__ m1,
            const float* __restrict__ v1,
            const float* __restrict__ W2, const float* __restrict__ g2,
            const float* __restrict__ b2, const float* __restrict__ m2,
            const float* __restrict__ v2, float* __restrict__ prep) {
  int t = threadIdx.x;
  for (int i = t; i < 224; i += 256) {
    int c = i & 31;
    prep[P_W1F + i] = W1[i] * (g1[c] * rsqrtf(v1[c] + EPS));
  }
  if (t < 32) {
    float s1 = g1[t] * rsqrtf(v1[t] + EPS);
    float s2 = g2[t] * rsqrtf(v2[t] + EPS);
    prep[P_B1F + t] = b1[t] - m1[t] * s1;
    prep[P_B2F + t] = b2[t] - m2[t] * s2;
  }
  unsigned short* wt = (unsigned short*)(prep + P_W2UT);
  for (int i = t; i < 1024; i += 256) {
    int k = i >> 5, c = i & 31;
    float s2 = g2[c] * rsqrtf(v2[c] + EPS);
    prep[P_W2L + i] = W2[(32 + k) * 32 + c] * s2;   // lower half, fp32
    wt[c * 32 + k] = f2bf(W2[k * 32 + c] * s2);     // upper half, bf16, [c][k]
  }
}

// ---- XCD-partitioned build (r7) ----
// r2 lesson: WRITE_SIZE stayed 65MB for a 4MB idx payload — one dirty 64B
// line per point, zero merging, because a pillar's idx line is written from
// blocks on all 8 XCDs (non-coherent L2s each write back their copy).
// Fix: pillar p owned by partition p&7; block b serves partition b&7
// (blockIdx round-robins across XCDs). Per-XCD dirty idx footprint ~0.7MB
// fits its 4MB L2 -> slot writes merge. Also emits input-ordered compact
// row8[N][8] (coalesced) so k_pillar gathers exactly 1 line per point.
__global__ __launch_bounds__(256)
void k_build(const float* __restrict__ points, const float* __restrict__ fc,
             const int* __restrict__ unq, int* __restrict__ cnt,
             int* __restrict__ idx, float* __restrict__ row8,
             int N, int chunk) {
  const int b = blockIdx.x, q = b & 7, g = b >> 3;
  const int t = threadIdx.x;
  const long base = (long)g * chunk;
  if (base >= N) return;
  const int end = (int)min(base + chunk, (long)N);
  const int ibase = (int)base;

  // 1) row copy: this block copies slice q of the chunk (each point once)
  {
    const int clen = end - ibase;
    const int s0 = ibase + (int)(((long)clen * q) >> 3);
    const int s1 = ibase + (int)(((long)clen * (q + 1)) >> 3);
    for (int i = s0 + t; i < s1; i += 256) {
      float4 a, bb;
      a.x = fc[3 * (size_t)i];
      a.y = fc[3 * (size_t)i + 1];
      a.z = fc[3 * (size_t)i + 2];
      a.w = points[5 * (size_t)i + 1];
      bb.x = points[5 * (size_t)i + 2];
      bb.y = points[5 * (size_t)i + 3];
      bb.z = points[5 * (size_t)i + 4];
      bb.w = 0.f;
      float4* dst = (float4*)(row8 + (size_t)i * 8);
      dst[0] = a;
      dst[1] = bb;
    }
  }

  // 2) filtered idx scatter over the whole chunk (only partition q's pillars)
  //    chunk%4==0 and N%4==0 -> int4 loads never cross `end`.
  for (int i = ibase + t * 4; i < end; i += 256 * 4) {
    int4 u = *(const int4*)(unq + i);
#pragma unroll
    for (int k = 0; k < 4; ++k) {
      int p = (k == 0) ? u.x : (k == 1) ? u.y : (k == 2) ? u.z : u.w;
      if (((p ^ q) & 7) == 0) {
        int slot = atomicAdd(&cnt[p * CSTRIDE], 1);
        if (slot < CAP) idx[p * CAP + slot] = i + k;
      }
    }
  }
}

// ---- one wave per pillar; MFMA for the 32x32 second linear ----
__global__ __launch_bounds__(256)
void k_pillar(const float* __restrict__ prep, const int* __restrict__ cnt,
              const int* __restrict__ idx, const float* __restrict__ row8,
              float* __restrict__ out, int npil) {
  __shared__ __align__(16) float fbuf[4][CAP * 8];            // 12 KB
  __shared__ __align__(16) unsigned short hbuf[4][CAP * 32];  // 24 KB
  __shared__ __align__(16) unsigned short w2t[1024];          // 2 KB (block)
  __shared__ float sumb[4][32];

  const int t = threadIdx.x, w = t >> 6, lane = t & 63;

  // stage W2-upper^T (bf16) once per block
  ((uint2*)w2t)[t] = ((const uint2*)(prep + P_W2UT))[t];
  __syncthreads();   // only block-level barrier

  const int p = blockIdx.x * 4 + w;
  if (p >= npil) return;
  int n = cnt[p * CSTRIDE];
  n = n < CAP ? n : CAP;

  const int c = lane & 31, half = lane >> 5;

  // phase 0: gather this pillar's rows — one 32B-aligned row per point,
  // exactly 1 cache line each; row8 (32MB) is Infinity-Cache-resident.
  const int* idxp = idx + (size_t)p * CAP;
  for (int s = lane; s < n; s += 64) {
    int i = idxp[s];
    const floatx4* src = (const floatx4*)(row8 + (size_t)i * 8);
    floatx4 A = src[0], B = src[1];
    floatx4* d4 = (floatx4*)(fbuf[w] + s * 8);
    d4[0] = A;
    d4[1] = B;
  }
  __builtin_amdgcn_wave_barrier();

  // folded weights (L1-hot across pillars)
  float w1c[7];
#pragma unroll
  for (int r = 0; r < 7; ++r) w1c[r] = prep[P_W1F + r * 32 + c];
  const float b1c = prep[P_B1F + c];
  const float b2c = prep[P_B2F + c];

  // phase 1: h = relu(f . w1f + b1f); fp32 partial sums; bf16 rows to LDS
  float ps = 0.f;
  for (int j = half; j < n; j += 2) {
    const float* f = fbuf[w] + j * 8;
    floatx4 fa = *(const floatx4*)f, fb = *(const floatx4*)(f + 4);
    float d = fa.x * w1c[0];
    d = fmaf(fa.y, w1c[1], d);
    d = fmaf(fa.z, w1c[2], d);
    d = fmaf(fa.w, w1c[3], d);
    d = fmaf(fb.x, w1c[4], d);
    d = fmaf(fb.y, w1c[5], d);
    d = fmaf(fb.z, w1c[6], d);
    float h = fmaxf(d + b1c, 0.f);
    ps += h;
    hbuf[w][j * 32 + c] = f2bf(h);
  }
  ps += __shfl_xor(ps, 32);          // cross-half channel sum
  if (half == 0) sumb[w][c] = ps;
  __builtin_amdgcn_wave_barrier();

  // phase 2: pc[c] = b2f + (sum_k sumh[k]*w2l[k][c]) / n   (same-wave LDS RAW)
  float acc = 0.f;
  const floatx4* sb4 = (const floatx4*)sumb[w];
#pragma unroll
  for (int kq = 0; kq < 8; ++kq) {
    floatx4 sv = sb4[kq];
    acc = fmaf(sv.x, prep[P_W2L + (kq * 4 + 0) * 32 + c], acc);
    acc = fmaf(sv.y, prep[P_W2L + (kq * 4 + 1) * 32 + c], acc);
    acc = fmaf(sv.z, prep[P_W2L + (kq * 4 + 2) * 32 + c], acc);
    acc = fmaf(sv.w, prep[P_W2L + (kq * 4 + 3) * 32 + c], acc);
  }
  const float inv_n = (n > 0) ? 1.f / (float)n : 1.f;
  const float pc = fmaf(inv_n, acc, b2c);

  // phase 3: Q = H(bf16) @ W2u via MFMA; masked max over rows
  const int m16 = lane & 15, q4 = lane >> 4;
  short8 bf0 = *(const short8*)(w2t + m16 * 32 + q4 * 8);
  short8 bf1 = *(const short8*)(w2t + (m16 + 16) * 32 + q4 * 8);
  float m0 = -INFINITY, m1 = -INFINITY;
  const int ntiles = (n + 15) >> 4;
  for (int rt = 0; rt < ntiles; ++rt) {
    short8 af = *(const short8*)(hbuf[w] + (rt * 16 + m16) * 32 + q4 * 8);
    floatx4 z = {0.f, 0.f, 0.f, 0.f};
    floatx4 a0 = __builtin_amdgcn_mfma_f32_16x16x32_bf16(af, bf0, z, 0, 0, 0);
    floatx4 a1 = __builtin_amdgcn_mfma_f32_16x16x32_bf16(af, bf1, z, 0, 0, 0);
    const int rowb = rt * 16 + q4 * 4;
#pragma unroll
    for (int r = 0; r < 4; ++r) {
      if (rowb + r < n) {          // mask tail-tile garbage rows
        m0 = fmaxf(m0, a0[r]);
        m1 = fmaxf(m1, a1[r]);
      }
    }
  }
  // reduce over the 4 row-groups (lanes differing in bits 4,5)
  m0 = fmaxf(m0, __shfl_xor(m0, 16));
  m0 = fmaxf(m0, __shfl_xor(m0, 32));
  m1 = fmaxf(m1, __shfl_xor(m1, 16));
  m1 = fmaxf(m1, __shfl_xor(m1, 32));

  if (lane < 32) {
    float q = (lane & 16) ? m1 : m0;     // cc = lane for lanes 0..31
    out[p * 32 + lane] = fmaxf(q + pc, 0.f);  // relu(max+pc): s2>0 monotone
  }
}

extern "C" void kernel_launch(void* const* d_in, const int* in_sizes, int n_in,
                              void* d_out, int out_size, void* d_ws, size_t ws_size,
                              hipStream_t stream) {
  const float* points = (const float*)d_in[0];
  const float* fc     = (const float*)d_in[1];
  const int*   unq    = (const int*)d_in[2];
  const float* W1 = (const float*)d_in[3];
  const float* g1 = (const float*)d_in[4];
  const float* b1 = (const float*)d_in[5];
  const float* m1 = (const float*)d_in[6];
  const float* v1 = (const float*)d_in[7];
  const float* W2 = (const float*)d_in[8];
  const float* g2 = (const float*)d_in[9];
  const float* b2 = (const float*)d_in[10];
  const float* m2 = (const float*)d_in[11];
  const float* v2 = (const float*)d_in[12];

  const int N    = in_sizes[0] / 5;  // 1,000,000
  const int NPIL = out_size / 32;    // 30,000

  float* ws = (float*)d_ws;
  int* cnt = (int*)ws;
  const size_t cnt_f  = ((size_t)NPIL * CSTRIDE + 255) & ~(size_t)255;
  float* prep = ws + cnt_f;
  int* idx = (int*)(prep + PREP_F);
  const size_t idx_f = ((size_t)NPIL * CAP + 255) & ~(size_t)255;
  float* row8 = prep + PREP_F + idx_f;

  hipMemsetAsync(cnt, 0, (size_t)NPIL * CSTRIDE * sizeof(int), stream);

  k_prep<<<1, 256, 0, stream>>>(W1, g1, b1, m1, v1, W2, g2, b2, m2, v2, prep);

  // chunk: multiple of 1024 so int4 loads of unq stay aligned & tail-free
  const int chunk = (((N + NGROUPS - 1) / NGROUPS) + 1023) & ~1023;
  k_build<<<NGROUPS * 8, 256, 0, stream>>>(points, fc, unq, cnt, idx, row8,
                                           N, chunk);

  const int nbp = (NPIL + 3) / 4;
  k_pillar<<<nbp, 256, 0, stream>>>(prep, cnt, idx, row8, (float*)d_out, NPIL);
}